// Round 8
// baseline (168.806 us; speedup 1.0000x reference)
//
#include <hip/hip_runtime.h>
#include <cstdint>
#include <cstddef>

// Problem constants: B=1024, T=12, D=512
#define Bsz 1024
#define Tsz 12
#define Dsz 512

#define TILE 64    // block tile 64(j) x 64(i); 4 waves as 2x2 of 32x32
#define BK   32    // K-chunk (32 f16 = 64 B = 4 x 16B chunks per row)
#define NIB  (Bsz / TILE)   // 16 i-tiles per column

typedef _Float16 h4    __attribute__((ext_vector_type(4)));
typedef _Float16 f16x8 __attribute__((ext_vector_type(8)));
typedef float    f32x4 __attribute__((ext_vector_type(4)));

// fp32 -> f16 hi/lo split (hi = rne(x), lo = rne(x - hi)).
__device__ __forceinline__ void cvt_store(const float4 v, _Float16* hp, _Float16* lp) {
    _Float16 hx = (_Float16)v.x, hy = (_Float16)v.y,
             hz = (_Float16)v.z, hw = (_Float16)v.w;
    h4 hh = {hx, hy, hz, hw};
    h4 ll = {(_Float16)(v.x - (float)hx), (_Float16)(v.y - (float)hy),
             (_Float16)(v.z - (float)hz), (_Float16)(v.w - (float)hw)};
    *(h4*)hp = hh;
    *(h4*)lp = ll;
}

// Async global->LDS DMA, 16 B per lane (dest = wave-uniform base + lane*16).
__device__ __forceinline__ void async_load16(const void* g, void* l) {
    __builtin_amdgcn_global_load_lds(
        (const __attribute__((address_space(1))) void*)g,
        (__attribute__((address_space(3))) void*)l, 16, 0, 0);
}

// Pre-split pass: convert a t-chunk of P and X (strided [B,T,D] fp32) into
// compact [nt][B][D] f16 hi/lo arrays. Each element converted exactly ONCE
// (vs once per consuming block in the in-loop scheme = 8-16x less VALU).
__global__ __launch_bounds__(256) void split_kernel(
    const float* __restrict__ P, const float* __restrict__ X,
    _Float16* __restrict__ Ph, _Float16* __restrict__ Pl,
    _Float16* __restrict__ Xh, _Float16* __restrict__ Xl,
    int t0, int nt)
{
    const int e4 = blockIdx.x * 256 + threadIdx.x;   // float4 index
    const int n4 = nt * Bsz * (Dsz / 4);
    if (e4 >= n4) return;
    const int d4   = e4 & (Dsz / 4 - 1);
    const int rest = e4 >> 7;               // tz*Bsz + b
    const int b    = rest & (Bsz - 1);
    const int tz   = rest >> 10;
    const size_t src = ((size_t)b * Tsz + (t0 + tz)) * Dsz + d4 * 4;
    const size_t dst = ((size_t)tz * Bsz + b) * Dsz + d4 * 4;
    cvt_store(*(const float4*)(P + src), Ph + dst, Pl + dst);
    cvt_store(*(const float4*)(X + src), Xh + dst, Xl + dst);
}

// Fused GEMM + tile softmax-partials on pre-split f16 hi/lo inputs.
// K-loop: pure DMA staging (no VALU) -> ds_read_b128 frags -> 3-term MFMA
// (hi*hi + hi*lo + lo*hi; dropped lo*lo ~2^-22 relative).
__global__ __launch_bounds__(256) void gemm_fused_kernel(
    const _Float16* __restrict__ Ph, const _Float16* __restrict__ Pl,
    const _Float16* __restrict__ Xh, const _Float16* __restrict__ Xl,
    float* __restrict__ pm,        // [Tsz*Bsz*NIB] tile max
    float* __restrict__ ps,        // [Tsz*Bsz*NIB] tile sum exp
    int*   __restrict__ pa,        // [Tsz*Bsz*NIB] tile argmax (global i)
    float* __restrict__ diag,      // [Tsz*Bsz]
    int t0)
{
    const int tz = blockIdx.z;
    const int t  = t0 + tz;
    const int bx = blockIdx.x;
    const int ib = bx * TILE;           // i tile (n-dim)
    const int jb = blockIdx.y * TILE;   // j tile (m-dim)
    const int tid  = threadIdx.x;
    const int lane = tid & 63;
    const int w    = tid >> 6;          // wave 0..3
    const int jw   = (w & 1) * 32;      // wave j-offset
    const int iw   = (w >> 1) * 32;     // wave i-offset
    const int ml   = lane & 15;
    const int quad = lane >> 4;

    __shared__ _Float16 Ps[2][TILE][BK];   // [0]=hi [1]=lo, 64B rows
    __shared__ _Float16 Xs[2][TILE][BK];
    __shared__ float sm_m[TILE][2];
    __shared__ float sm_s[TILE][2];
    __shared__ int   sm_a[TILE][2];

    f32x4 acc[2][2];
#pragma unroll
    for (int r = 0; r < 2; ++r)
#pragma unroll
        for (int c = 0; c < 2; ++c) acc[r][c] = (f32x4){0.f, 0.f, 0.f, 0.f};

    const size_t toff = (size_t)tz * Bsz * Dsz;
    // Wave w owns one of the 4 staging arrays (wave-uniform branch).
    const _Float16* gbase;
    _Float16 (*lbase)[BK];
    if      (w == 0) { gbase = Ph + toff + (size_t)jb * Dsz; lbase = Ps[0]; }
    else if (w == 1) { gbase = Pl + toff + (size_t)jb * Dsz; lbase = Ps[1]; }
    else if (w == 2) { gbase = Xh + toff + (size_t)ib * Dsz; lbase = Xs[0]; }
    else             { gbase = Xl + toff + (size_t)ib * Dsz; lbase = Xs[1]; }
    const int srow = lane >> 2;        // 0..15 row-within-group
    const int sch  = lane & 3;         // 16B chunk within 64B row

    for (int k0 = 0; k0 < Dsz; k0 += BK) {
        // ---- stage: 4 DMA issues per wave, 16 rows each, zero VALU ----
#pragma unroll
        for (int u = 0; u < 4; ++u) {
            const int row = u * 16 + srow;
            async_load16(gbase + (size_t)row * Dsz + k0 + sch * 8,
                         &lbase[u * 16][0]);
        }
        __syncthreads();

        // ---- fragments: one ds_read_b128 per operand ----
        f16x8 ah[2], al[2], bh[2], bl[2];
#pragma unroll
        for (int r = 0; r < 2; ++r) {
            ah[r] = *(const f16x8*)&Ps[0][jw + r * 16 + ml][quad * 8];
            al[r] = *(const f16x8*)&Ps[1][jw + r * 16 + ml][quad * 8];
        }
#pragma unroll
        for (int c = 0; c < 2; ++c) {
            bh[c] = *(const f16x8*)&Xs[0][iw + c * 16 + ml][quad * 8];
            bl[c] = *(const f16x8*)&Xs[1][iw + c * 16 + ml][quad * 8];
        }

        // ---- MFMA: hi*hi + hi*lo + lo*hi ----
#pragma unroll
        for (int r = 0; r < 2; ++r)
#pragma unroll
            for (int c = 0; c < 2; ++c) {
                acc[r][c] = __builtin_amdgcn_mfma_f32_16x16x32_f16(ah[r], bh[c], acc[r][c], 0, 0, 0);
                acc[r][c] = __builtin_amdgcn_mfma_f32_16x16x32_f16(ah[r], bl[c], acc[r][c], 0, 0, 0);
                acc[r][c] = __builtin_amdgcn_mfma_f32_16x16x32_f16(al[r], bh[c], acc[r][c], 0, 0, 0);
            }
        __syncthreads();
    }

    // ---- diag extraction (global index test) ----
#pragma unroll
    for (int r = 0; r < 2; ++r)
#pragma unroll
        for (int v = 0; v < 4; ++v) {
            const int jg = jb + jw + r * 16 + quad * 4 + v;
#pragma unroll
            for (int c = 0; c < 2; ++c) {
                const int ig = ib + iw + c * 16 + ml;
                if (ig == jg) diag[(size_t)t * Bsz + jg] = acc[r][c][v];
            }
        }

    // ---- per-row (j) partial over this wave's 32-i slice ----
    // acc[r][c][v] sits at row j = jw+r*16+quad*4+v, col i = iw+c*16+ml.
#pragma unroll
    for (int r = 0; r < 2; ++r)
#pragma unroll
        for (int v = 0; v < 4; ++v) {
            float m = acc[r][0][v];
            int   ai = iw + ml;
            {
                const float val = acc[r][1][v];
                if (val > m) { m = val; ai = iw + 16 + ml; }
            }
#pragma unroll
            for (int off = 1; off < 16; off <<= 1) {
                float om = __shfl_xor(m, off);
                int   oi = __shfl_xor(ai, off);
                if (om > m || (om == m && oi < ai)) { m = om; ai = oi; }
            }
            float s = __expf(acc[r][0][v] - m) + __expf(acc[r][1][v] - m);
#pragma unroll
            for (int off = 1; off < 16; off <<= 1) s += __shfl_xor(s, off);

            if (ml == 0) {
                const int row = jw + r * 16 + quad * 4 + v;
                sm_m[row][iw >> 5] = m;
                sm_s[row][iw >> 5] = s;
                sm_a[row][iw >> 5] = ib + ai;   // global i
            }
        }
    __syncthreads();

    // ---- combine the two i-halves, write tile partials ----
    if (tid < TILE) {
        const int row = tid;
        const float m0 = sm_m[row][0], m1 = sm_m[row][1];
        const float s0 = sm_s[row][0], s1 = sm_s[row][1];
        float M; int A;
        if (m1 > m0) { M = m1; A = sm_a[row][1]; }   // tie -> half 0 (smaller i)
        else         { M = m0; A = sm_a[row][0]; }
        const float S = s0 * __expf(m0 - M) + s1 * __expf(m1 - M);
        const size_t slot = ((size_t)t * Bsz + (jb + row)) * NIB + bx;
        pm[slot] = M;
        ps[slot] = S;
        pa[slot] = A;
    }
}

__global__ void zero_out_kernel(float* out) {
    if (threadIdx.x < 2) out[threadIdx.x] = 0.0f;
}

// One thread per (t,j) column: merge NIB tile partials, 48 block atomics.
__global__ __launch_bounds__(256) void combine_kernel(
    const float* __restrict__ pm,
    const float* __restrict__ ps,
    const int*   __restrict__ pa,
    const float* __restrict__ diag,
    float* __restrict__ out)
{
    const int col = blockIdx.x * 256 + threadIdx.x;   // 0..Tsz*Bsz-1
    const int j = col & (Bsz - 1);

    const size_t base = (size_t)col * NIB;
    float M = pm[base]; int A = pa[base];
#pragma unroll
    for (int b = 1; b < NIB; ++b) {
        const float mb = pm[base + b];
        if (mb > M) { M = mb; A = pa[base + b]; }   // tie -> earlier b = smaller i
    }
    float S = 0.0f;
#pragma unroll
    for (int b = 0; b < NIB; ++b) S += ps[base + b] * __expf(pm[base + b] - M);

    const float lse = M + logf(S);
    float sl = lse - diag[col];
    float sc = (A == j) ? 1.0f : 0.0f;

#pragma unroll
    for (int off = 1; off < 64; off <<= 1) {
        sl += __shfl_xor(sl, off);
        sc += __shfl_xor(sc, off);
    }

    __shared__ float wl[4], wc[4];
    const int w = threadIdx.x >> 6;
    if ((threadIdx.x & 63) == 0) { wl[w] = sl; wc[w] = sc; }
    __syncthreads();
    if (threadIdx.x == 0) {
        const float inv = 1.0f / (float)(Bsz * Tsz);
        atomicAdd(&out[0], (wl[0] + wl[1] + wl[2] + wl[3]) * inv);  // -loss
        atomicAdd(&out[1], (wc[0] + wc[1] + wc[2] + wc[3]) * inv);  // accuracy
    }
}

extern "C" void kernel_launch(void* const* d_in, const int* in_sizes, int n_in,
                              void* d_out, int out_size, void* d_ws, size_t ws_size,
                              hipStream_t stream) {
    const float* P = (const float*)d_in[0];  // predictions [B,T,D]
    const float* X = (const float*)d_in[1];  // x_future_encoded [B,T,D]
    float* out = (float*)d_out;

    const size_t ncol  = (size_t)Bsz * Tsz;          // 12288
    const size_t nslot = ncol * NIB;                 // 196608
    float* pm   = (float*)d_ws;
    float* ps   = pm + nslot;
    int*   pa   = (int*)(ps + nslot);
    float* diag = (float*)(pa + nslot);
    char*  splitbuf = (char*)(diag + ncol);
    // align to 256 B
    splitbuf = (char*)(((uintptr_t)splitbuf + 255) & ~(uintptr_t)255);

    const size_t perArr = (size_t)Bsz * Dsz * sizeof(_Float16);  // 1 MiB per t
    const size_t perT   = 4 * perArr;                            // 4 MiB per t
    const size_t used   = (size_t)(splitbuf - (char*)d_ws);
    size_t avail = ws_size > used ? ws_size - used : 0;
    int ntc = (int)(avail / perT);
    if (ntc > Tsz) ntc = Tsz;
    if (ntc < 1) ntc = 1;

    for (int t0 = 0; t0 < Tsz; t0 += ntc) {
        const int nt = (Tsz - t0) < ntc ? (Tsz - t0) : ntc;
        _Float16* Ph = (_Float16*)splitbuf;
        _Float16* Pl = Ph + (size_t)nt * Bsz * Dsz;
        _Float16* Xh = Pl + (size_t)nt * Bsz * Dsz;
        _Float16* Xl = Xh + (size_t)nt * Bsz * Dsz;

        const int n4 = nt * Bsz * (Dsz / 4);
        split_kernel<<<dim3((n4 + 255) / 256), dim3(256), 0, stream>>>(
            P, X, Ph, Pl, Xh, Xl, t0, nt);

        gemm_fused_kernel<<<dim3(NIB, Bsz / TILE, nt), dim3(256), 0, stream>>>(
            Ph, Pl, Xh, Xl, pm, ps, pa, diag, t0);
    }

    zero_out_kernel<<<dim3(1), dim3(64), 0, stream>>>(out);

    combine_kernel<<<dim3((int)(ncol / 256)), dim3(256), 0, stream>>>(
        pm, ps, pa, diag, out);
}

// Round 9
// 152.182 us; speedup vs baseline: 1.1092x; 1.1092x over previous
//
#include <hip/hip_runtime.h>
#include <cstdint>
#include <cstddef>

// Problem constants: B=1024, T=12, D=512
#define Bsz 1024
#define Tsz 12
#define Dsz 512

#define TILE 128   // block tile 128(j) x 128(i); 4 waves as 2x2 of 64x64
#define BK   32    // K-chunk (32 f16 = 64 B = 4 x 16B chunks per row)
#define NIB  (Bsz / TILE)   // 8 i-tiles per column

typedef _Float16 h4    __attribute__((ext_vector_type(4)));
typedef _Float16 f16x8 __attribute__((ext_vector_type(8)));
typedef float    f32x4 __attribute__((ext_vector_type(4)));

// fp32 -> f16 hi/lo split (hi = rne(x), lo = rne(x - hi)).
__device__ __forceinline__ void cvt_store(const float4 v, _Float16* hp, _Float16* lp) {
    _Float16 hx = (_Float16)v.x, hy = (_Float16)v.y,
             hz = (_Float16)v.z, hw = (_Float16)v.w;
    h4 hh = {hx, hy, hz, hw};
    h4 ll = {(_Float16)(v.x - (float)hx), (_Float16)(v.y - (float)hy),
             (_Float16)(v.z - (float)hz), (_Float16)(v.w - (float)hw)};
    *(h4*)hp = hh;
    *(h4*)lp = ll;
}

// Async global->LDS DMA, 16 B per lane (dest = wave-uniform base + lane*16).
__device__ __forceinline__ void async_load16(const void* g, void* l) {
    __builtin_amdgcn_global_load_lds(
        (const __attribute__((address_space(1))) void*)g,
        (__attribute__((address_space(3))) void*)l, 16, 0, 0);
}

// Pre-split pass: convert P and X ([B,T,D] fp32, t-chunk) into compact
// [nt][B][D] f16 hi/lo arrays. Each element converted exactly ONCE.
__global__ __launch_bounds__(256) void split_kernel(
    const float* __restrict__ P, const float* __restrict__ X,
    _Float16* __restrict__ Ph, _Float16* __restrict__ Pl,
    _Float16* __restrict__ Xh, _Float16* __restrict__ Xl,
    int t0, int nt)
{
    const int e4 = blockIdx.x * 256 + threadIdx.x;   // float4 index
    const int n4 = nt * Bsz * (Dsz / 4);
    if (e4 >= n4) return;
    const int d4   = e4 & (Dsz / 4 - 1);
    const int rest = e4 >> 7;               // tz*Bsz + b
    const int b    = rest & (Bsz - 1);
    const int tz   = rest >> 10;
    const size_t src = ((size_t)b * Tsz + (t0 + tz)) * Dsz + d4 * 4;
    const size_t dst = ((size_t)tz * Bsz + b) * Dsz + d4 * 4;
    cvt_store(*(const float4*)(P + src), Ph + dst, Pl + dst);
    cvt_store(*(const float4*)(X + src), Xh + dst, Xl + dst);
}

// Fused GEMM + tile softmax-partials on pre-split f16 hi/lo inputs.
// 128x128 tile (4 waves, 4x4 16x16 accs each): per wave-iter 16 ds_read_b128
// feed 48 MFMA -> MFMA-bound K-loop with zero VALU. 3 blocks/CU via
// __launch_bounds__(256,3).
__global__ __launch_bounds__(256, 3) void gemm_fused_kernel(
    const _Float16* __restrict__ Ph, const _Float16* __restrict__ Pl,
    const _Float16* __restrict__ Xh, const _Float16* __restrict__ Xl,
    float* __restrict__ pm,        // [Tsz*Bsz*NIB] tile max
    float* __restrict__ ps,        // [Tsz*Bsz*NIB] tile sum exp
    int*   __restrict__ pa,        // [Tsz*Bsz*NIB] tile argmax (global i)
    float* __restrict__ diag,      // [Tsz*Bsz]
    int t0)
{
    const int tz = blockIdx.z;
    const int t  = t0 + tz;
    const int bx = blockIdx.x;
    const int ib = bx * TILE;           // i tile (n-dim)
    const int jb = blockIdx.y * TILE;   // j tile (m-dim)
    const int tid  = threadIdx.x;
    const int lane = tid & 63;
    const int w    = tid >> 6;          // wave 0..3
    const int jw   = (w & 1) * 64;      // wave j-offset
    const int iw   = (w >> 1) * 64;     // wave i-offset
    const int ml   = lane & 15;
    const int quad = lane >> 4;

    __shared__ _Float16 Psh[TILE][BK];  // P hi
    __shared__ _Float16 Psl[TILE][BK];  // P lo
    __shared__ _Float16 Xsh[TILE][BK];  // X hi
    __shared__ _Float16 Xsl[TILE][BK];  // X lo
    __shared__ float sm_m[TILE][2];
    __shared__ float sm_s[TILE][2];
    __shared__ int   sm_a[TILE][2];

    f32x4 acc[4][4];
#pragma unroll
    for (int r = 0; r < 4; ++r)
#pragma unroll
        for (int c = 0; c < 4; ++c) acc[r][c] = (f32x4){0.f, 0.f, 0.f, 0.f};

    const size_t toff = (size_t)tz * Bsz * Dsz;
    // Wave w stages one whole array (wave-uniform base): 8 issues x 16 rows.
    const _Float16* gbase;
    _Float16* lbase;
    if      (w == 0) { gbase = Ph + toff + (size_t)jb * Dsz; lbase = &Psh[0][0]; }
    else if (w == 1) { gbase = Pl + toff + (size_t)jb * Dsz; lbase = &Psl[0][0]; }
    else if (w == 2) { gbase = Xh + toff + (size_t)ib * Dsz; lbase = &Xsh[0][0]; }
    else             { gbase = Xl + toff + (size_t)ib * Dsz; lbase = &Xsl[0][0]; }
    const int srow = lane >> 2;        // 0..15 row within issue-group
    const int sch  = lane & 3;         // 16B chunk within 64B row

    for (int k0 = 0; k0 < Dsz; k0 += BK) {
        // ---- stage: 8 DMA issues per wave (16 rows each), zero VALU ----
#pragma unroll
        for (int u = 0; u < 8; ++u) {
            const int row = u * 16 + srow;
            async_load16(gbase + (size_t)row * Dsz + k0 + sch * 8,
                         lbase + u * 16 * BK);
        }
        __syncthreads();

        // ---- fragments: one ds_read_b128 per operand ----
        f16x8 ah[4], al[4], bh[4], bl[4];
#pragma unroll
        for (int r = 0; r < 4; ++r) {
            ah[r] = *(const f16x8*)&Psh[jw + r * 16 + ml][quad * 8];
            al[r] = *(const f16x8*)&Psl[jw + r * 16 + ml][quad * 8];
        }
#pragma unroll
        for (int c = 0; c < 4; ++c) {
            bh[c] = *(const f16x8*)&Xsh[iw + c * 16 + ml][quad * 8];
            bl[c] = *(const f16x8*)&Xsl[iw + c * 16 + ml][quad * 8];
        }

        // ---- MFMA: hi*hi + hi*lo + lo*hi ----
#pragma unroll
        for (int r = 0; r < 4; ++r)
#pragma unroll
            for (int c = 0; c < 4; ++c) {
                acc[r][c] = __builtin_amdgcn_mfma_f32_16x16x32_f16(ah[r], bh[c], acc[r][c], 0, 0, 0);
                acc[r][c] = __builtin_amdgcn_mfma_f32_16x16x32_f16(ah[r], bl[c], acc[r][c], 0, 0, 0);
                acc[r][c] = __builtin_amdgcn_mfma_f32_16x16x32_f16(al[r], bh[c], acc[r][c], 0, 0, 0);
            }
        __syncthreads();
    }

    // ---- diag extraction (global index test) ----
#pragma unroll
    for (int r = 0; r < 4; ++r)
#pragma unroll
        for (int v = 0; v < 4; ++v) {
            const int jg = jb + jw + r * 16 + quad * 4 + v;
#pragma unroll
            for (int c = 0; c < 4; ++c) {
                const int ig = ib + iw + c * 16 + ml;
                if (ig == jg) diag[(size_t)t * Bsz + jg] = acc[r][c][v];
            }
        }

    // ---- per-row (j) partial over this wave's 64-i slice ----
    // acc[r][c][v] sits at row j = jw+r*16+quad*4+v, col i = iw+c*16+ml.
#pragma unroll
    for (int r = 0; r < 4; ++r)
#pragma unroll
        for (int v = 0; v < 4; ++v) {
            float m = acc[r][0][v];
            int   ai = iw + ml;
#pragma unroll
            for (int c = 1; c < 4; ++c) {
                const float val = acc[r][c][v];
                if (val > m) { m = val; ai = iw + c * 16 + ml; }
            }
#pragma unroll
            for (int off = 1; off < 16; off <<= 1) {
                float om = __shfl_xor(m, off);
                int   oi = __shfl_xor(ai, off);
                if (om > m || (om == m && oi < ai)) { m = om; ai = oi; }
            }
            float s = 0.0f;
#pragma unroll
            for (int c = 0; c < 4; ++c) s += __expf(acc[r][c][v] - m);
#pragma unroll
            for (int off = 1; off < 16; off <<= 1) s += __shfl_xor(s, off);

            if (ml == 0) {
                const int row = jw + r * 16 + quad * 4 + v;
                sm_m[row][iw >> 6] = m;
                sm_s[row][iw >> 6] = s;
                sm_a[row][iw >> 6] = ib + ai;   // global i
            }
        }
    __syncthreads();

    // ---- combine the two i-halves, write tile partials ----
    if (tid < TILE) {
        const int row = tid;
        const float m0 = sm_m[row][0], m1 = sm_m[row][1];
        const float s0 = sm_s[row][0], s1 = sm_s[row][1];
        float M; int A;
        if (m1 > m0) { M = m1; A = sm_a[row][1]; }   // tie -> half 0 (smaller i)
        else         { M = m0; A = sm_a[row][0]; }
        const float S = s0 * __expf(m0 - M) + s1 * __expf(m1 - M);
        const size_t slot = ((size_t)t * Bsz + (jb + row)) * NIB + bx;
        pm[slot] = M;
        ps[slot] = S;
        pa[slot] = A;
    }
}

__global__ void zero_out_kernel(float* out) {
    if (threadIdx.x < 2) out[threadIdx.x] = 0.0f;
}

// One thread per (t,j) column: merge NIB tile partials, 48 block atomics.
__global__ __launch_bounds__(256) void combine_kernel(
    const float* __restrict__ pm,
    const float* __restrict__ ps,
    const int*   __restrict__ pa,
    const float* __restrict__ diag,
    float* __restrict__ out)
{
    const int col = blockIdx.x * 256 + threadIdx.x;   // 0..Tsz*Bsz-1
    const int j = col & (Bsz - 1);

    const size_t base = (size_t)col * NIB;
    float M = pm[base]; int A = pa[base];
#pragma unroll
    for (int b = 1; b < NIB; ++b) {
        const float mb = pm[base + b];
        if (mb > M) { M = mb; A = pa[base + b]; }   // tie -> earlier b = smaller i
    }
    float S = 0.0f;
#pragma unroll
    for (int b = 0; b < NIB; ++b) S += ps[base + b] * __expf(pm[base + b] - M);

    const float lse = M + logf(S);
    float sl = lse - diag[col];
    float sc = (A == j) ? 1.0f : 0.0f;

#pragma unroll
    for (int off = 1; off < 64; off <<= 1) {
        sl += __shfl_xor(sl, off);
        sc += __shfl_xor(sc, off);
    }

    __shared__ float wl[4], wc[4];
    const int w = threadIdx.x >> 6;
    if ((threadIdx.x & 63) == 0) { wl[w] = sl; wc[w] = sc; }
    __syncthreads();
    if (threadIdx.x == 0) {
        const float inv = 1.0f / (float)(Bsz * Tsz);
        atomicAdd(&out[0], (wl[0] + wl[1] + wl[2] + wl[3]) * inv);  // -loss
        atomicAdd(&out[1], (wc[0] + wc[1] + wc[2] + wc[3]) * inv);  // accuracy
    }
}

extern "C" void kernel_launch(void* const* d_in, const int* in_sizes, int n_in,
                              void* d_out, int out_size, void* d_ws, size_t ws_size,
                              hipStream_t stream) {
    const float* P = (const float*)d_in[0];  // predictions [B,T,D]
    const float* X = (const float*)d_in[1];  // x_future_encoded [B,T,D]
    float* out = (float*)d_out;

    const size_t ncol  = (size_t)Bsz * Tsz;          // 12288
    const size_t nslot = ncol * NIB;                 // 98304
    float* pm   = (float*)d_ws;
    float* ps   = pm + nslot;
    int*   pa   = (int*)(ps + nslot);
    float* diag = (float*)(pa + nslot);
    char*  splitbuf = (char*)(diag + ncol);
    splitbuf = (char*)(((uintptr_t)splitbuf + 255) & ~(uintptr_t)255);

    const size_t perArr = (size_t)Bsz * Dsz * sizeof(_Float16);  // 1 MiB per t
    const size_t perT   = 4 * perArr;                            // 4 MiB per t
    const size_t used   = (size_t)(splitbuf - (char*)d_ws);
    size_t avail = ws_size > used ? ws_size - used : 0;
    int ntc = (int)(avail / perT);
    if (ntc > Tsz) ntc = Tsz;
    if (ntc < 1) ntc = 1;

    for (int t0 = 0; t0 < Tsz; t0 += ntc) {
        const int nt = (Tsz - t0) < ntc ? (Tsz - t0) : ntc;
        _Float16* Ph = (_Float16*)splitbuf;
        _Float16* Pl = Ph + (size_t)nt * Bsz * Dsz;
        _Float16* Xh = Pl + (size_t)nt * Bsz * Dsz;
        _Float16* Xl = Xh + (size_t)nt * Bsz * Dsz;

        const int n4 = nt * Bsz * (Dsz / 4);
        split_kernel<<<dim3((n4 + 255) / 256), dim3(256), 0, stream>>>(
            P, X, Ph, Pl, Xh, Xl, t0, nt);

        gemm_fused_kernel<<<dim3(NIB, Bsz / TILE, nt), dim3(256), 0, stream>>>(
            Ph, Pl, Xh, Xl, pm, ps, pa, diag, t0);
    }

    zero_out_kernel<<<dim3(1), dim3(64), 0, stream>>>(out);

    combine_kernel<<<dim3((int)(ncol / 256)), dim3(256), 0, stream>>>(
        pm, ps, pa, diag, out);
}